// Round 3
// baseline (259.552 us; speedup 1.0000x reference)
//
#include <hip/hip_runtime.h>
#include <math.h>

constexpr int B_ = 8192;
constexpr int T_ = 512;
constexpr int TILE = 16;                 // steps per LDS flush tile
constexpr int NTILE = T_ / TILE;         // 32
constexpr int ROWB = TILE * 16 + 16;     // 272 B per session row in LDS (pad -> conflict-free)
constexpr size_t PACK_BYTES = (size_t)B_ * T_;   // 4 MB

__device__ __forceinline__ float sp_(float x) {
    return fmaxf(x, 0.0f) + log1pf(expf(-fabsf(x)));  // stable softplus
}
__device__ __forceinline__ float sg_(float x) { return 1.0f / (1.0f + expf(-x)); }
__device__ __forceinline__ float clipf(float x, float lo, float hi) { return fminf(fmaxf(x, lo), hi); }
__device__ __forceinline__ float sel(bool c, float a, float b) { return c ? a : b; }

// ---------------- pass 1: compress input to 1 byte/step, scan-friendly layout ----------------
// packed flat index = ((b>>6)*NTILE + (t>>4))*1024 + (b&63)*16 + (t&15)  == thread id below
__global__ __launch_bounds__(256) void pack_kernel(const float* __restrict__ in,
                                                   unsigned char* __restrict__ pk) {
    const int tid  = blockIdx.x * 256 + threadIdx.x;      // 0 .. B*T-1
    const int ti   = tid & 15;
    const int lane = (tid >> 4) & 63;
    const int tile = (tid >> 10) & (NTILE - 1);
    const int grp  = tid >> 15;
    const int b = (grp << 6) | lane;
    const int t = (tile << 4) | ti;
    const float* base = in + ((size_t)b * T_ + t) * 8;
    const float4 a = *reinterpret_cast<const float4*>(base);
    const float  r = base[4];                              // rewards broadcast: r[0] suffices
    const int cc = a.y > 0.5f ? 1 : (a.z > 0.5f ? 2 : (a.w > 0.5f ? 3 : 0));
    pk[tid] = (unsigned char)(cc | ((r > 0.5f) ? 4 : 0));
}

// ---------------- pass 2: sequential scan, packed input, LDS-transposed coalesced output ----------------
__global__ __launch_bounds__(64, 1) void castro_scan_packed(
    const unsigned char* __restrict__ pk,
    const float* __restrict__ p,
    float* __restrict__ out)
{
    __shared__ unsigned char lds[64 * ROWB];   // 17408 B
    const int l   = threadIdx.x;
    const int blk = blockIdx.x;

    // ---- parameter transform ----
    const float beta_r = clipf(sp_(p[0]), 0.01f, 20.0f);
    const float lapse  = clipf(sg_(p[1]), 0.01f, 0.99f);
    const float prior  = clipf(sp_(p[2]), 0.01f, 0.99f);
    const float alpha  = clipf(sg_(p[3]), 0.01f, 0.99f);
    const float decay  = clipf(sg_(p[4]), 0.01f, 0.99f);
    const float ab1    = p[5];
    const float ab2    = p[6];
    const float pers   = sp_(p[7]);
    const float sw     = p[8];
    const float gamma  = sp_(p[10]);
    const float temp   = clipf(sp_(p[11]) + 1e-6f, 1e-6f, 100.0f);
    const float beta_p = sp_(p[12]);

    const float brt = beta_r / temp;
    const float l4  = lapse * 0.25f;
    const float oml = 1.0f - lapse;

    // ---- carry state ----
    float q0 = prior, q1 = prior, q2 = prior, q3 = prior;
    float c0 = 0.f, c1 = 0.f, c2 = 0.f, c3 = 0.f;
    int   oldc = -1;
    float tsls = 0.0f;
    float expl = alpha;

    const uint4* __restrict__ pkt =
        reinterpret_cast<const uint4*>(pk + (size_t)blk * (NTILE * 1024)) + l;  // +64 per tile
    float4* __restrict__ out4 = reinterpret_cast<float4*>(out);
    const size_t ob = (size_t)blk * 64;

    uint4 cur = pkt[0];
    for (int k = 0; k < NTILE; ++k) {
        const uint4 nxt = pkt[(k + 1 < NTILE ? k + 1 : k) * 64];   // prefetch next tile

#pragma unroll
        for (int ti = 0; ti < TILE; ++ti) {
            const unsigned int word = (ti < 4) ? cur.x : (ti < 8) ? cur.y : (ti < 12) ? cur.z : cur.w;
            const unsigned int byte = (word >> (8 * (ti & 3))) & 0xffu;
            const int  cc = (int)(byte & 3u);
            const bool rf = (byte & 4u) != 0u;

            const float target = sel(rf, 1.0f, -gamma);   // rv - gamma*(1-rv), rv in {0,1}

            const bool same = (cc == oldc);
            tsls = sel(same, tsls + 1.0f, 0.0f);
            expl *= (1.0f - 1e-3f);

            const bool i0 = (cc == 0), i1 = (cc == 1), i2 = (cc == 2), i3 = (cc == 3);
            q0 = sel(i0, target, q0);  c0 += sel(i0, 1.0f, 0.0f);
            q1 = sel(i1, target, q1);  c1 += sel(i1, 1.0f, 0.0f);
            q2 = sel(i2, target, q2);  c2 += sel(i2, 1.0f, 0.0f);
            q3 = sel(i3, target, q3);  c3 += sel(i3, 1.0f, 0.0f);

            const float qm = 0.25f * ((q0 + q1) + (q2 + q3));
            const float omd = (1.0f - expl) * decay;
            const float eqd = expl * decay * qm;
            q0 = fmaf(omd, q0, eqd);
            q1 = fmaf(omd, q1, eqd);
            q2 = fmaf(omd, q2, eqd);
            q3 = fmaf(omd, q3, eqd);

            const float s0 = fmaf(brt, q0, beta_p * __logf(1.0f + c0));
            const float s1 = fmaf(brt, q1, beta_p * __logf(1.0f + c1));
            const float s2 = fmaf(brt, q2, beta_p * __logf(1.0f + c2));
            const float s3 = fmaf(brt, q3, beta_p * __logf(1.0f + c3));
            const float m  = fmaxf(fmaxf(s0, s1), fmaxf(s2, s3));
            const float e0 = __expf(s0 - m);
            const float e1 = __expf(s1 - m);
            const float e2 = __expf(s2 - m);
            const float e3 = __expf(s3 - m);
            const float iz = oml / ((e0 + e1) + (e2 + e3));

            float l0 = __logf(fmaf(e0, iz, l4));
            float l1 = __logf(fmaf(e1, iz, l4));
            float l2 = __logf(fmaf(e2, iz, l4));
            float l3 = __logf(fmaf(e3, iz, l4));

            const float bcc = sel(same, pers, sw) + __logf(tsls + 1.0f);
            const int cc2 = cc ^ 2;
            l0 += sel(i0, bcc, 0.0f) + sel(oldc == 0, ab1, 0.0f) + sel(cc2 == 0, ab2, 0.0f);
            l1 += sel(i1, bcc, 0.0f) + sel(oldc == 1, ab1, 0.0f) + sel(cc2 == 1, ab2, 0.0f);
            l2 += sel(i2, bcc, 0.0f) + sel(oldc == 2, ab1, 0.0f) + sel(cc2 == 2, ab2, 0.0f);
            l3 += sel(i3, bcc, 0.0f) + sel(oldc == 3, ab1, 0.0f) + sel(cc2 == 3, ab2, 0.0f);

            *reinterpret_cast<float4*>(&lds[l * ROWB + ti * 16]) = make_float4(l0, l1, l2, l3);
            oldc = cc;
        }

        __syncthreads();   // LDS writes -> reads
#pragma unroll
        for (int pp = 0; pp < 16; ++pp) {
            const int s  = pp * 4 + (l >> 4);    // session within block
            const int st = l & 15;               // step within tile
            const float4 v = *reinterpret_cast<const float4*>(&lds[s * ROWB + st * 16]);
            out4[(ob + s) * T_ + k * TILE + st] = v;   // 1 KB contiguous per wave-store
        }
        __syncthreads();   // LDS reads done before next tile overwrites

        cur = nxt;
    }
}

// ---------------- fallback (ws too small): round-2 direct kernel ----------------
__global__ __launch_bounds__(64, 1) void castro_scan_direct(
    const float* __restrict__ in, const float* __restrict__ p, float* __restrict__ out)
{
    const int b = blockIdx.x * 64 + threadIdx.x;
    if (b >= B_) return;
    const float beta_r = clipf(sp_(p[0]), 0.01f, 20.0f);
    const float lapse  = clipf(sg_(p[1]), 0.01f, 0.99f);
    const float prior  = clipf(sp_(p[2]), 0.01f, 0.99f);
    const float alpha  = clipf(sg_(p[3]), 0.01f, 0.99f);
    const float decay  = clipf(sg_(p[4]), 0.01f, 0.99f);
    const float ab1 = p[5], ab2 = p[6];
    const float pers = sp_(p[7]), sw = p[8];
    const float gamma = sp_(p[10]);
    const float temp = clipf(sp_(p[11]) + 1e-6f, 1e-6f, 100.0f);
    const float beta_p = sp_(p[12]);
    const float brt = beta_r / temp, l4 = lapse * 0.25f, oml = 1.0f - lapse;
    float q0 = prior, q1 = prior, q2 = prior, q3 = prior;
    float c0 = 0, c1 = 0, c2 = 0, c3 = 0, tsls = 0, expl = alpha;
    int oldc = -1;
    const float4* ip = reinterpret_cast<const float4*>(in + (size_t)b * T_ * 8);
    float4* op = reinterpret_cast<float4*>(out + (size_t)b * T_ * 4);
    for (int t = 0; t < T_; ++t) {
        const float4 a = ip[2 * t]; const float4 r = ip[2 * t + 1];
        const int cc = a.y > 0.5f ? 1 : (a.z > 0.5f ? 2 : (a.w > 0.5f ? 3 : 0));
        const float rv = a.x * r.x + a.y * r.y + a.z * r.z + a.w * r.w;
        const float target = rv - gamma * (1.0f - rv);
        const bool same = (cc == oldc);
        tsls = sel(same, tsls + 1.0f, 0.0f);
        expl *= (1.0f - 1e-3f);
        const bool i0 = cc == 0, i1 = cc == 1, i2 = cc == 2, i3 = cc == 3;
        q0 = sel(i0, target, q0); c0 += sel(i0, 1.f, 0.f);
        q1 = sel(i1, target, q1); c1 += sel(i1, 1.f, 0.f);
        q2 = sel(i2, target, q2); c2 += sel(i2, 1.f, 0.f);
        q3 = sel(i3, target, q3); c3 += sel(i3, 1.f, 0.f);
        const float qm = 0.25f * ((q0 + q1) + (q2 + q3));
        const float omd = (1.0f - expl) * decay, eqd = expl * decay * qm;
        q0 = fmaf(omd, q0, eqd); q1 = fmaf(omd, q1, eqd);
        q2 = fmaf(omd, q2, eqd); q3 = fmaf(omd, q3, eqd);
        const float s0 = fmaf(brt, q0, beta_p * __logf(1.0f + c0));
        const float s1 = fmaf(brt, q1, beta_p * __logf(1.0f + c1));
        const float s2 = fmaf(brt, q2, beta_p * __logf(1.0f + c2));
        const float s3 = fmaf(brt, q3, beta_p * __logf(1.0f + c3));
        const float m = fmaxf(fmaxf(s0, s1), fmaxf(s2, s3));
        const float e0 = __expf(s0 - m), e1 = __expf(s1 - m), e2 = __expf(s2 - m), e3 = __expf(s3 - m);
        const float iz = oml / ((e0 + e1) + (e2 + e3));
        float l0 = __logf(fmaf(e0, iz, l4)), l1 = __logf(fmaf(e1, iz, l4));
        float l2 = __logf(fmaf(e2, iz, l4)), l3 = __logf(fmaf(e3, iz, l4));
        const float bcc = sel(same, pers, sw) + __logf(tsls + 1.0f);
        const int cc2 = cc ^ 2;
        l0 += sel(i0, bcc, 0.f) + sel(oldc == 0, ab1, 0.f) + sel(cc2 == 0, ab2, 0.f);
        l1 += sel(i1, bcc, 0.f) + sel(oldc == 1, ab1, 0.f) + sel(cc2 == 1, ab2, 0.f);
        l2 += sel(i2, bcc, 0.f) + sel(oldc == 2, ab1, 0.f) + sel(cc2 == 2, ab2, 0.f);
        l3 += sel(i3, bcc, 0.f) + sel(oldc == 3, ab1, 0.f) + sel(cc2 == 3, ab2, 0.f);
        op[t] = make_float4(l0, l1, l2, l3);
        oldc = cc;
    }
}

extern "C" void kernel_launch(void* const* d_in, const int* in_sizes, int n_in,
                              void* d_out, int out_size, void* d_ws, size_t ws_size,
                              hipStream_t stream) {
    const float* inputs = (const float*)d_in[0];   // [8192, 512, 8] f32
    const float* params = (const float*)d_in[1];   // [13] f32
    float* out = (float*)d_out;                    // [8192, 512, 4] f32

    if (ws_size >= PACK_BYTES) {
        unsigned char* pk = (unsigned char*)d_ws;
        pack_kernel<<<dim3((B_ * T_) / 256), dim3(256), 0, stream>>>(inputs, pk);
        castro_scan_packed<<<dim3(B_ / 64), dim3(64), 0, stream>>>(pk, params, out);
    } else {
        castro_scan_direct<<<dim3(B_ / 64), dim3(64), 0, stream>>>(inputs, params, out);
    }
}

// Round 5
// 111.574 us; speedup vs baseline: 2.3263x; 2.3263x over previous
//
#include <hip/hip_runtime.h>
#include <math.h>

constexpr int B_ = 8192;
constexpr int T_ = 512;
constexpr int CH = 16;                     // steps per chunk / LDS tile
constexpr int NCH = T_ / CH;               // 32 chunks
constexpr int GRPS = B_ / 64;              // 128 session-groups
constexpr int ROWB = CH * 16 + 16;         // 272 B LDS row (pad)
constexpr size_t PACK_BYTES = (size_t)B_ * T_;          // 4 MB
constexpr size_t PLANE = (size_t)GRPS * NCH * 64;       // 262144 floats per snapshot plane
constexpr int NPLANES = 11;                              // q0..3, c0..3, tsls, expl, oldc
constexpr size_t SNAP_BYTES = PLANE * NPLANES * sizeof(float);   // 11 MB

__device__ __forceinline__ float sp_(float x) {
    return fmaxf(x, 0.0f) + log1pf(expf(-fabsf(x)));  // stable softplus
}
__device__ __forceinline__ float sg_(float x) { return 1.0f / (1.0f + expf(-x)); }
__device__ __forceinline__ float clipf(float x, float lo, float hi) { return fminf(fmaxf(x, lo), hi); }
__device__ __forceinline__ float sel(bool c, float a, float b) { return c ? a : b; }

// carry state — all named scalars, statically indexed
struct CS { float q0, q1, q2, q3, c0, c1, c2, c3, tsls, expl; int oldc; };

// One carry step. Used by BOTH seq_carry and chunk_logits -> bit-identical restart.
// NOTE: updates s.oldc = cc at the end (round-4 bug was dropping this).
__device__ __forceinline__ void step_carry(CS& s, unsigned int byte, float gamma, float decay,
                                           bool& same, bool& i0, bool& i1, bool& i2, bool& i3,
                                           int& cc_out) {
    const int  cc = (int)(byte & 3u);
    const bool rf = (byte & 4u) != 0u;
    const float target = sel(rf, 1.0f, -gamma);          // rv - gamma*(1-rv), rv in {0,1}
    same = (cc == s.oldc);
    s.tsls = sel(same, s.tsls + 1.0f, 0.0f);
    s.expl *= (1.0f - 1e-3f);
    i0 = (cc == 0); i1 = (cc == 1); i2 = (cc == 2); i3 = (cc == 3);
    s.q0 = sel(i0, target, s.q0);  s.c0 += sel(i0, 1.0f, 0.0f);
    s.q1 = sel(i1, target, s.q1);  s.c1 += sel(i1, 1.0f, 0.0f);
    s.q2 = sel(i2, target, s.q2);  s.c2 += sel(i2, 1.0f, 0.0f);
    s.q3 = sel(i3, target, s.q3);  s.c3 += sel(i3, 1.0f, 0.0f);
    const float qm  = 0.25f * ((s.q0 + s.q1) + (s.q2 + s.q3));
    const float omd = (1.0f - s.expl) * decay;
    const float eqd = (s.expl * decay) * qm;
    s.q0 = fmaf(omd, s.q0, eqd);
    s.q1 = fmaf(omd, s.q1, eqd);
    s.q2 = fmaf(omd, s.q2, eqd);
    s.q3 = fmaf(omd, s.q3, eqd);
    s.oldc = cc;          // <-- the fix
    cc_out = cc;
}

// ---------------- pass 1: compress input to 1 byte/step ----------------
// packed byte index = ((b>>6)*NCH + (t>>4))*1024 + (b&63)*16 + (t&15)
__global__ __launch_bounds__(256) void pack_kernel(const float* __restrict__ in,
                                                   unsigned char* __restrict__ pk) {
    const int tid  = blockIdx.x * 256 + threadIdx.x;      // 0 .. B*T-1
    const int ti   = tid & 15;
    const int lane = (tid >> 4) & 63;
    const int tile = (tid >> 10) & (NCH - 1);
    const int grp  = tid >> 15;
    const int b = (grp << 6) | lane;
    const int t = (tile << 4) | ti;
    const float* base = in + ((size_t)b * T_ + t) * 8;
    const float4 a = *reinterpret_cast<const float4*>(base);
    const float  r = base[4];
    const int cc = a.y > 0.5f ? 1 : (a.z > 0.5f ? 2 : (a.w > 0.5f ? 3 : 0));
    pk[tid] = (unsigned char)(cc | ((r > 0.5f) ? 4 : 0));
}

// ---------------- pass 2: sequential carry-only scan, snapshot every CH steps ----------------
__global__ __launch_bounds__(64, 1) void seq_carry(const unsigned char* __restrict__ pk,
                                                   const float* __restrict__ p,
                                                   float* __restrict__ snap) {
    const int l   = threadIdx.x;
    const int grp = blockIdx.x;

    const float prior = clipf(sp_(p[2]), 0.01f, 0.99f);
    const float alpha = clipf(sg_(p[3]), 0.01f, 0.99f);
    const float decay = clipf(sg_(p[4]), 0.01f, 0.99f);
    const float gamma = sp_(p[10]);

    CS s;
    s.q0 = s.q1 = s.q2 = s.q3 = prior;
    s.c0 = s.c1 = s.c2 = s.c3 = 0.0f;
    s.tsls = 0.0f; s.expl = alpha; s.oldc = -1;

    const uint4* __restrict__ pkt =
        reinterpret_cast<const uint4*>(pk + (size_t)grp * (NCH * 1024)) + l;

    uint4 cur = pkt[0];
    for (int k = 0; k < NCH; ++k) {
        // snapshot = state BEFORE chunk k
        const size_t sb = (size_t)(grp * NCH + k) * 64 + l;
        snap[0 * PLANE + sb] = s.q0;  snap[1 * PLANE + sb] = s.q1;
        snap[2 * PLANE + sb] = s.q2;  snap[3 * PLANE + sb] = s.q3;
        snap[4 * PLANE + sb] = s.c0;  snap[5 * PLANE + sb] = s.c1;
        snap[6 * PLANE + sb] = s.c2;  snap[7 * PLANE + sb] = s.c3;
        snap[8 * PLANE + sb] = s.tsls;
        snap[9 * PLANE + sb] = s.expl;
        snap[10 * PLANE + sb] = (float)s.oldc;

        const uint4 nxt = pkt[(k + 1 < NCH ? k + 1 : k) * 64];
#pragma unroll
        for (int ti = 0; ti < CH; ++ti) {
            const unsigned int word = (ti < 4) ? cur.x : (ti < 8) ? cur.y : (ti < 12) ? cur.z : cur.w;
            const unsigned int byte = (word >> (8 * (ti & 3))) & 0xffu;
            bool same, i0, i1, i2, i3; int cc;
            step_carry(s, byte, gamma, decay, same, i0, i1, i2, i3, cc);
        }
        cur = nxt;
    }
}

// ---------------- pass 3: per-chunk logits, fully parallel (B*NCH threads) ----------------
__global__ __launch_bounds__(64) void chunk_logits(const unsigned char* __restrict__ pk,
                                                   const float* __restrict__ p,
                                                   const float* __restrict__ snap,
                                                   float* __restrict__ out) {
    __shared__ unsigned char lds[64 * ROWB];
    const int l   = threadIdx.x;
    const int bid = blockIdx.x;          // = grp*NCH + k
    const int k   = bid & (NCH - 1);
    const int grp = bid >> 5;            // NCH == 32

    // full param transform
    const float beta_r = clipf(sp_(p[0]), 0.01f, 20.0f);
    const float lapse  = clipf(sg_(p[1]), 0.01f, 0.99f);
    const float decay  = clipf(sg_(p[4]), 0.01f, 0.99f);
    const float ab1    = p[5];
    const float ab2    = p[6];
    const float pers   = sp_(p[7]);
    const float sw     = p[8];
    const float gamma  = sp_(p[10]);
    const float temp   = clipf(sp_(p[11]) + 1e-6f, 1e-6f, 100.0f);
    const float beta_p = sp_(p[12]);
    const float brt = beta_r / temp;
    const float l4  = lapse * 0.25f;
    const float oml = 1.0f - lapse;

    // restart state from snapshot (exact f32 carry)
    const size_t sb = (size_t)bid * 64 + l;
    CS s;
    s.q0 = snap[0 * PLANE + sb];  s.q1 = snap[1 * PLANE + sb];
    s.q2 = snap[2 * PLANE + sb];  s.q3 = snap[3 * PLANE + sb];
    s.c0 = snap[4 * PLANE + sb];  s.c1 = snap[5 * PLANE + sb];
    s.c2 = snap[6 * PLANE + sb];  s.c3 = snap[7 * PLANE + sb];
    s.tsls = snap[8 * PLANE + sb];
    s.expl = snap[9 * PLANE + sb];
    s.oldc = (int)snap[10 * PLANE + sb];

    const uint4 cur = reinterpret_cast<const uint4*>(pk)[(size_t)bid * 64 + l];

#pragma unroll
    for (int ti = 0; ti < CH; ++ti) {
        const unsigned int word = (ti < 4) ? cur.x : (ti < 8) ? cur.y : (ti < 12) ? cur.z : cur.w;
        const unsigned int byte = (word >> (8 * (ti & 3))) & 0xffu;
        const int prev = s.oldc;
        bool same, i0, i1, i2, i3; int cc;
        step_carry(s, byte, gamma, decay, same, i0, i1, i2, i3, cc);

        const float s0 = fmaf(brt, s.q0, beta_p * __logf(1.0f + s.c0));
        const float s1 = fmaf(brt, s.q1, beta_p * __logf(1.0f + s.c1));
        const float s2 = fmaf(brt, s.q2, beta_p * __logf(1.0f + s.c2));
        const float s3 = fmaf(brt, s.q3, beta_p * __logf(1.0f + s.c3));
        const float m  = fmaxf(fmaxf(s0, s1), fmaxf(s2, s3));
        const float e0 = __expf(s0 - m);
        const float e1 = __expf(s1 - m);
        const float e2 = __expf(s2 - m);
        const float e3 = __expf(s3 - m);
        const float iz = oml / ((e0 + e1) + (e2 + e3));

        float l0 = __logf(fmaf(e0, iz, l4));
        float l1 = __logf(fmaf(e1, iz, l4));
        float l2 = __logf(fmaf(e2, iz, l4));
        float l3 = __logf(fmaf(e3, iz, l4));

        const float bcc = sel(same, pers, sw) + __logf(s.tsls + 1.0f);
        const int cc2 = cc ^ 2;
        l0 += sel(i0, bcc, 0.0f) + sel(prev == 0, ab1, 0.0f) + sel(cc2 == 0, ab2, 0.0f);
        l1 += sel(i1, bcc, 0.0f) + sel(prev == 1, ab1, 0.0f) + sel(cc2 == 1, ab2, 0.0f);
        l2 += sel(i2, bcc, 0.0f) + sel(prev == 2, ab1, 0.0f) + sel(cc2 == 2, ab2, 0.0f);
        l3 += sel(i3, bcc, 0.0f) + sel(prev == 3, ab1, 0.0f) + sel(cc2 == 3, ab2, 0.0f);

        *reinterpret_cast<float4*>(&lds[l * ROWB + ti * 16]) = make_float4(l0, l1, l2, l3);
    }

    __syncthreads();
    float4* __restrict__ out4 = reinterpret_cast<float4*>(out);
#pragma unroll
    for (int pp = 0; pp < 16; ++pp) {
        const int ss = pp * 4 + (l >> 4);    // session within group
        const int st = l & 15;               // step within chunk
        const float4 v = *reinterpret_cast<const float4*>(&lds[ss * ROWB + st * 16]);
        out4[((size_t)(grp * 64 + ss)) * T_ + k * CH + st] = v;   // coalesced wave-store
    }
}

// ---------------- fallback: monolithic packed scan (ws >= 4MB only) ----------------
__global__ __launch_bounds__(64, 1) void castro_scan_packed(
    const unsigned char* __restrict__ pk, const float* __restrict__ p, float* __restrict__ out)
{
    __shared__ unsigned char lds[64 * ROWB];
    const int l = threadIdx.x, blk = blockIdx.x;
    const float beta_r = clipf(sp_(p[0]), 0.01f, 20.0f);
    const float lapse  = clipf(sg_(p[1]), 0.01f, 0.99f);
    const float prior  = clipf(sp_(p[2]), 0.01f, 0.99f);
    const float alpha  = clipf(sg_(p[3]), 0.01f, 0.99f);
    const float decay  = clipf(sg_(p[4]), 0.01f, 0.99f);
    const float ab1 = p[5], ab2 = p[6];
    const float pers = sp_(p[7]), sw = p[8];
    const float gamma = sp_(p[10]);
    const float temp = clipf(sp_(p[11]) + 1e-6f, 1e-6f, 100.0f);
    const float beta_p = sp_(p[12]);
    const float brt = beta_r / temp, l4 = lapse * 0.25f, oml = 1.0f - lapse;
    CS s; s.q0 = s.q1 = s.q2 = s.q3 = prior;
    s.c0 = s.c1 = s.c2 = s.c3 = 0.0f; s.tsls = 0.0f; s.expl = alpha; s.oldc = -1;
    const uint4* pkt = reinterpret_cast<const uint4*>(pk + (size_t)blk * (NCH * 1024)) + l;
    float4* out4 = reinterpret_cast<float4*>(out);
    uint4 cur = pkt[0];
    for (int k = 0; k < NCH; ++k) {
        const uint4 nxt = pkt[(k + 1 < NCH ? k + 1 : k) * 64];
#pragma unroll
        for (int ti = 0; ti < CH; ++ti) {
            const unsigned int word = (ti < 4) ? cur.x : (ti < 8) ? cur.y : (ti < 12) ? cur.z : cur.w;
            const unsigned int byte = (word >> (8 * (ti & 3))) & 0xffu;
            const int prev = s.oldc;
            bool same, i0, i1, i2, i3; int cc;
            step_carry(s, byte, gamma, decay, same, i0, i1, i2, i3, cc);
            const float s0 = fmaf(brt, s.q0, beta_p * __logf(1.0f + s.c0));
            const float s1 = fmaf(brt, s.q1, beta_p * __logf(1.0f + s.c1));
            const float s2 = fmaf(brt, s.q2, beta_p * __logf(1.0f + s.c2));
            const float s3 = fmaf(brt, s.q3, beta_p * __logf(1.0f + s.c3));
            const float m = fmaxf(fmaxf(s0, s1), fmaxf(s2, s3));
            const float e0 = __expf(s0 - m), e1 = __expf(s1 - m);
            const float e2 = __expf(s2 - m), e3 = __expf(s3 - m);
            const float iz = oml / ((e0 + e1) + (e2 + e3));
            float l0 = __logf(fmaf(e0, iz, l4)), l1 = __logf(fmaf(e1, iz, l4));
            float l2 = __logf(fmaf(e2, iz, l4)), l3 = __logf(fmaf(e3, iz, l4));
            const float bcc = sel(same, pers, sw) + __logf(s.tsls + 1.0f);
            const int cc2 = cc ^ 2;
            l0 += sel(i0, bcc, 0.f) + sel(prev == 0, ab1, 0.f) + sel(cc2 == 0, ab2, 0.f);
            l1 += sel(i1, bcc, 0.f) + sel(prev == 1, ab1, 0.f) + sel(cc2 == 1, ab2, 0.f);
            l2 += sel(i2, bcc, 0.f) + sel(prev == 2, ab1, 0.f) + sel(cc2 == 2, ab2, 0.f);
            l3 += sel(i3, bcc, 0.f) + sel(prev == 3, ab1, 0.f) + sel(cc2 == 3, ab2, 0.f);
            *reinterpret_cast<float4*>(&lds[l * ROWB + ti * 16]) = make_float4(l0, l1, l2, l3);
        }
        __syncthreads();
#pragma unroll
        for (int pp = 0; pp < 16; ++pp) {
            const int ss = pp * 4 + (l >> 4);
            const int st = l & 15;
            const float4 v = *reinterpret_cast<const float4*>(&lds[ss * ROWB + st * 16]);
            out4[((size_t)(blk * 64 + ss)) * T_ + k * CH + st] = v;
        }
        __syncthreads();
        cur = nxt;
    }
}

extern "C" void kernel_launch(void* const* d_in, const int* in_sizes, int n_in,
                              void* d_out, int out_size, void* d_ws, size_t ws_size,
                              hipStream_t stream) {
    const float* inputs = (const float*)d_in[0];   // [8192, 512, 8] f32
    const float* params = (const float*)d_in[1];   // [13] f32
    float* out = (float*)d_out;                    // [8192, 512, 4] f32

    if (ws_size >= PACK_BYTES + SNAP_BYTES) {
        unsigned char* pk = (unsigned char*)d_ws;
        float* snap = (float*)((char*)d_ws + PACK_BYTES);
        pack_kernel<<<dim3((B_ * T_) / 256), dim3(256), 0, stream>>>(inputs, pk);
        seq_carry<<<dim3(GRPS), dim3(64), 0, stream>>>(pk, params, snap);
        chunk_logits<<<dim3(GRPS * NCH), dim3(64), 0, stream>>>(pk, params, snap, out);
    } else if (ws_size >= PACK_BYTES) {
        unsigned char* pk = (unsigned char*)d_ws;
        pack_kernel<<<dim3((B_ * T_) / 256), dim3(256), 0, stream>>>(inputs, pk);
        castro_scan_packed<<<dim3(GRPS), dim3(64), 0, stream>>>(pk, params, out);
    }
}